// Round 5
// baseline (4654.771 us; speedup 1.0000x reference)
//
#include <hip/hip_runtime.h>

// Problem constants (B=8, N=4096, n_points=1024, n_samples=32, D_PTS=6, MLPS=[64,64,128])
#define NPTS  4096
#define NB    8
#define NC    1024
#define NSAMP 32
#define DP    6
#define C0    9      // 3 + D_PTS
#define C3    128
#define ROWS_TOT 262144   // NB*NC*NSAMP

// Workspace layout (bytes). Requires ws_size >= ~184 MB.
// ws+0 .. 16KB: ablation-probe dump (dead data, never read back)
#define OFF_SS   (32ull<<10)     // 3 layers x {scale[128], shift[128]}
#define OFF_H0   (1ull<<20)      // h0: 262144 x 9 f32 (9.4 MB)
#define OFF_Y0   (16ull<<20)     // y0: 262144 x 64 f32 (67 MB)
#define OFF_Y1   (96ull<<20)     // y1: 262144 x 64 f32 (67 MB)
#define OFF_PSUM (168ull<<20)    // per-block channel sums   [C][NBLK] (max 4 MB)
#define OFF_PSQ  (172ull<<20)    // per-block channel sumsq  [C][NBLK] (max 4 MB)
#define OFF_GMX  (176ull<<20)    // per-centroid channel max [8192][128] (4 MB)
#define OFF_GMN  (180ull<<20)    // per-centroid channel min [8192][128] (4 MB)

#define ABL_REPS 5

typedef unsigned long long ull;

// Exact (no-FMA) squared distance to match numpy rounding; sum order ((x+y)+z).
__device__ __forceinline__ float sqdist_noc(float x, float y, float z,
                                            float cx, float cy, float cz) {
  #pragma clang fp contract(off)
  float dx = x - cx, dy = y - cy, dz = z - cz;
  return dx * dx + dy * dy + dz * dz;
}

// 64-bit DPP move (two 32-bit halves, same ctrl; old=self so masked lanes keep value)
template <int CTRL, int RM>
__device__ __forceinline__ ull dpp_mov_u64(ull x) {
  int lo = (int)(unsigned)(x & 0xFFFFFFFFull);
  int hi = (int)(unsigned)(x >> 32);
  int rlo = __builtin_amdgcn_update_dpp(lo, lo, CTRL, RM, 0xf, false);
  int rhi = __builtin_amdgcn_update_dpp(hi, hi, CTRL, RM, 0xf, false);
  return ((ull)(unsigned)rhi << 32) | (unsigned)rlo;
}

__device__ __forceinline__ ull umax64(ull a, ull b) { return a > b ? a : b; }

// wave64 u64 max reduce, all-VALU (no scalar round-trips); result in lane 63.
__device__ __forceinline__ ull wave64_umax(ull x) {
  x = umax64(x, dpp_mov_u64<0x111, 0xf>(x));  // row_shr:1
  x = umax64(x, dpp_mov_u64<0x112, 0xf>(x));  // row_shr:2
  x = umax64(x, dpp_mov_u64<0x114, 0xf>(x));  // row_shr:4
  x = umax64(x, dpp_mov_u64<0x118, 0xf>(x));  // row_shr:8
  x = umax64(x, dpp_mov_u64<0x142, 0xa>(x));  // row_bcast:15 -> rows 1,3
  x = umax64(x, dpp_mov_u64<0x143, 0xc>(x));  // row_bcast:31 -> rows 2,3
  return x;
}

// ---------------------------------------------------------------------------
// FPS (real): identical to R4. 1023 sequential steps, 512 thr, 8 pts/thread.
// ---------------------------------------------------------------------------
__global__ __launch_bounds__(512)
void fps_kernel(const float* __restrict__ xyz, float* __restrict__ cent) {
  const int b = blockIdx.x;
  const int t = threadIdx.x;
  const float* X = xyz + (size_t)b * NPTS * 3;
  float* OC = cent + (size_t)b * NC * 3;

  __shared__ float4 sxyz[NPTS];                 // 64 KB
  __shared__ alignas(16) ull wk[2][8];
  __shared__ int sidx[NC];                      // 4 KB

  for (int p = t; p < NPTS; p += 512)
    sxyz[p] = make_float4(X[p * 3 + 0], X[p * 3 + 1], X[p * 3 + 2], 0.f);
  __syncthreads();

  float px[8], py[8], pz[8];
  #pragma unroll
  for (int i = 0; i < 8; i++) {
    float4 v = sxyz[t * 8 + i];
    px[i] = v.x; py[i] = v.y; pz[i] = v.z;
  }

  int last = 0;  // deterministic seed index 0
  for (int k = 1; k < NC; k++) {
    const int par = k & 1;
    if (t == 0) sidx[k - 1] = last;
    float4 c = sxyz[last];                      // broadcast read
    if ((last >> 3) == t) {                     // retire: NaN loses all compares
      int ii = last & 7;
      #pragma unroll
      for (int i = 0; i < 8; i++)
        if (i == ii) px[i] = __int_as_float(0x7FC00000);
    }

    float mx = -1.0f; int mj = 0;
    #pragma unroll
    for (int i = 0; i < 8; i++) {
      float sq = sqdist_noc(px[i], py[i], pz[i], c.x, c.y, c.z);
      if (sq > mx) { mx = sq; mj = i; }         // strict > keeps first index
    }
    ull key = (mx >= 0.f)
        ? ((ull)(unsigned)__float_as_uint(mx) << 12) |
          (unsigned)(4095 - (t * 8 + mj))       // tie -> smaller idx wins
        : 0ull;
    key = wave64_umax(key);

    if ((t & 63) == 63) wk[par][t >> 6] = key;  // leader = lane 63
    __syncthreads();
    const ulonglong2* W2 = (const ulonglong2*)&wk[par][0];
    ulonglong2 p0 = W2[0], p1 = W2[1], p2 = W2[2], p3 = W2[3];
    ull m0 = umax64(umax64(p0.x, p0.y), umax64(p1.x, p1.y));
    ull m1 = umax64(umax64(p2.x, p2.y), umax64(p3.x, p3.y));
    last = 4095 - (int)(umax64(m0, m1) & 0xFFFull);
  }
  if (t == 0) sidx[NC - 1] = last;
  __syncthreads();
  for (int i = t; i < NC; i += 512) {
    float4 c = sxyz[sidx[i]];
    OC[i * 3 + 0] = c.x;
    OC[i * 3 + 1] = c.y;
    OC[i * 3 + 2] = c.z;
  }
}

// ---------------------------------------------------------------------------
// ABLATION PROBE 1 (A+D+E): LDS publish -> barrier -> fold -> dependent
// sxyz[last] read. Junk keys (pure fn of t,k,rep) -- no dist, no DPP.
// Deterministic; dumps to dead ws region. x5 reps for top-5 visibility.
// ---------------------------------------------------------------------------
__global__ __launch_bounds__(512)
void fps_sync_probe(const float* __restrict__ xyz, int* __restrict__ dump) {
  const int b = blockIdx.x;
  const int t = threadIdx.x;
  const float* X = xyz + (size_t)b * NPTS * 3;
  __shared__ float4 sxyz[NPTS];
  __shared__ alignas(16) ull wk[2][8];
  for (int p = t; p < NPTS; p += 512)
    sxyz[p] = make_float4(X[p * 3 + 0], X[p * 3 + 1], X[p * 3 + 2], 0.f);
  __syncthreads();
  int last = 0;
  for (int rep = 0; rep < ABL_REPS; rep++) {
    for (int k = 1; k < NC; k++) {
      const int par = k & 1;
      unsigned jk = (unsigned)t * 2654435761u + (unsigned)k * 40503u + (unsigned)rep * 97u;
      ull key = ((ull)jk << 12) | (unsigned)(t & 0xFFF);   // junk, pure fn
      if ((t & 63) == 63) wk[par][t >> 6] = key;
      __syncthreads();
      const ulonglong2* W2 = (const ulonglong2*)&wk[par][0];
      ulonglong2 p0 = W2[0], p1 = W2[1], p2 = W2[2], p3 = W2[3];
      ull m0 = umax64(umax64(p0.x, p0.y), umax64(p1.x, p1.y));
      ull m1 = umax64(umax64(p2.x, p2.y), umax64(p3.x, p3.y));
      last = 4095 - (int)(umax64(m0, m1) & 0xFFFull);
      float4 c = sxyz[last];                               // dependent read (A)
      asm volatile("" :: "v"(c.x), "v"(c.y), "v"(c.z));    // keep live (rule #17)
    }
  }
  if (t == 0) dump[b] = last;
}

// ---------------------------------------------------------------------------
// ABLATION PROBE 2 (A+B+C): LCG centroid -> sxyz[last] read -> 8x sqdist +
// local argmax -> u64 pack -> 6-round DPP reduce. No barrier, no exchange.
// ---------------------------------------------------------------------------
__global__ __launch_bounds__(512)
void fps_compute_probe(const float* __restrict__ xyz, int* __restrict__ dump) {
  const int b = blockIdx.x;
  const int t = threadIdx.x;
  const float* X = xyz + (size_t)b * NPTS * 3;
  __shared__ float4 sxyz[NPTS];
  for (int p = t; p < NPTS; p += 512)
    sxyz[p] = make_float4(X[p * 3 + 0], X[p * 3 + 1], X[p * 3 + 2], 0.f);
  __syncthreads();
  float px[8], py[8], pz[8];
  #pragma unroll
  for (int i = 0; i < 8; i++) {
    float4 v = sxyz[t * 8 + i];
    px[i] = v.x; py[i] = v.y; pz[i] = v.z;
  }
  unsigned acc = 0;
  for (int rep = 0; rep < ABL_REPS; rep++) {
    unsigned lcg = 12345u + (unsigned)rep;
    for (int k = 1; k < NC; k++) {
      lcg = lcg * 1664525u + 1013904223u;       // uniform across threads
      int last = (int)(lcg & 0xFFFu);
      float4 c = sxyz[last];                    // dependent read (A)
      float mx = -1.0f; int mj = 0;
      #pragma unroll
      for (int i = 0; i < 8; i++) {
        float sq = sqdist_noc(px[i], py[i], pz[i], c.x, c.y, c.z);
        if (sq > mx) { mx = sq; mj = i; }
      }
      ull key = (mx >= 0.f)
          ? ((ull)(unsigned)__float_as_uint(mx) << 12) |
            (unsigned)(4095 - (t * 8 + mj))
          : 0ull;
      key = wave64_umax(key);
      asm volatile("" : "+v"(key));             // keep DPP chain live
      acc ^= (unsigned)key;
    }
  }
  if (t == 0) dump[NB + b] = (int)acc;
}

// ---------------------------------------------------------------------------
// query_ball + gather + concat (unchanged from R4)
// ---------------------------------------------------------------------------
#define BCAP 256
__global__ __launch_bounds__(256)
void ball_kernel(const float* __restrict__ xyz, const float* __restrict__ pts,
                 const float* __restrict__ cent, float* __restrict__ h0) {
  const int blk = blockIdx.x;       // b*NC + c
  const int b = blk >> 10;
  const int t = threadIdx.x;
  const float* X = xyz + (size_t)b * NPTS * 3;
  const float* P = pts + (size_t)b * NPTS * DP;
  const float cx = cent[(size_t)blk * 3 + 0];
  const float cy = cent[(size_t)blk * 3 + 1];
  const float cz = cent[(size_t)blk * 3 + 2];

  __shared__ int scount;
  __shared__ ull skeys[BCAP];
  __shared__ ull ssorted[BCAP];
  __shared__ int sel[NSAMP];
  if (t == 0) scount = 0;
  __syncthreads();

  #pragma unroll
  for (int i = 0; i < 16; i++) {
    int j = t * 16 + i;
    float sq = sqdist_noc(X[j * 3 + 0], X[j * 3 + 1], X[j * 3 + 2], cx, cy, cz);
    if (sq < 0.0017f) {                       // conservative guard
      float d = (sq > 0.f) ? sqrtf(sq) : 0.f; // exact per-reference norm
      if (d < 0.04f) {                        // strictly inside the clip value
        int pos = atomicAdd(&scount, 1);
        if (pos < BCAP)
          skeys[pos] = ((ull)(unsigned)__float_as_int(d) << 12) | (unsigned)j;
      }
    }
  }
  __syncthreads();
  const int M = min(scount, BCAP);

  if (t < M) {
    ull my = skeys[t];
    int r = 0;
    for (int j2 = 0; j2 < M; j2++) r += (skeys[j2] < my);
    ssorted[r] = my;
  }
  __syncthreads();

  if (t < NSAMP) {
    int v;
    if (t < M) {
      v = (int)(ssorted[t] & 0xFFFull);
    } else {
      int s = t - M;
      int idx = s;
      for (int it = 0; it < 40; it++) {
        int c = 0;
        for (int j2 = 0; j2 < M; j2++) c += ((int)(skeys[j2] & 0xFFFull) <= idx);
        int nidx = s + c;
        if (nidx == idx) break;
        idx = nidx;
      }
      v = idx;
    }
    sel[t] = v;
  }
  __syncthreads();

  float* H = h0 + (size_t)blk * NSAMP * C0;
  for (int e = t; e < NSAMP * C0; e += 256) {
    int k = e / C0;
    int c = e - k * C0;
    int j = sel[k];
    H[e] = (c < 3) ? X[j * 3 + c] : P[j * DP + (c - 3)];
  }
}

// ---------------------------------------------------------------------------
// dense0 (unchanged)
// ---------------------------------------------------------------------------
__global__ __launch_bounds__(256)
void dense0_kernel(const float* __restrict__ h0, const float* __restrict__ W,
                   const float* __restrict__ bias, float* __restrict__ yout,
                   float* __restrict__ psum, float* __restrict__ psq) {
  __shared__ float xs[64 * C0];
  __shared__ float ws[C0 * 64];
  __shared__ float red[2][16][64];
  const int blk = blockIdx.x, t = threadIdx.x;
  const size_t rbase = (size_t)blk * 64;
  for (int e = t; e < 64 * C0; e += 256) xs[e] = h0[rbase * C0 + e];
  for (int e = t; e < C0 * 64; e += 256) ws[e] = W[e];
  __syncthreads();
  const int rg = t >> 4, cg = t & 15;
  float acc[4][4];
  float4 bv = *(const float4*)(bias + cg * 4);
  #pragma unroll
  for (int r = 0; r < 4; r++) { acc[r][0] = bv.x; acc[r][1] = bv.y; acc[r][2] = bv.z; acc[r][3] = bv.w; }
  #pragma unroll
  for (int k = 0; k < C0; k++) {
    float4 wv = *(const float4*)(ws + k * 64 + cg * 4);
    #pragma unroll
    for (int r = 0; r < 4; r++) {
      float x = xs[(rg * 4 + r) * C0 + k];
      acc[r][0] = fmaf(x, wv.x, acc[r][0]);
      acc[r][1] = fmaf(x, wv.y, acc[r][1]);
      acc[r][2] = fmaf(x, wv.z, acc[r][2]);
      acc[r][3] = fmaf(x, wv.w, acc[r][3]);
    }
  }
  #pragma unroll
  for (int r = 0; r < 4; r++)
    *(float4*)(yout + (rbase + rg * 4 + r) * 64 + cg * 4) =
        make_float4(acc[r][0], acc[r][1], acc[r][2], acc[r][3]);
  #pragma unroll
  for (int c4 = 0; c4 < 4; c4++) {
    float s = 0.f, q = 0.f;
    #pragma unroll
    for (int r = 0; r < 4; r++) { float v = acc[r][c4]; s += v; q = fmaf(v, v, q); }
    red[0][rg][cg * 4 + c4] = s;
    red[1][rg][cg * 4 + c4] = q;
  }
  __syncthreads();
  if (t < 64) {
    float S = 0.f, Q = 0.f;
    #pragma unroll
    for (int g = 0; g < 16; g++) { S += red[0][g][t]; Q += red[1][g][t]; }
    psum[(size_t)t * 4096 + blk] = S;
    psq [(size_t)t * 4096 + blk] = Q;
  }
}

// ---------------------------------------------------------------------------
// dense mid (unchanged)
// ---------------------------------------------------------------------------
template <int RPB, int COUT, int CGN, int NBLKS, bool MM>
__global__ __launch_bounds__(256)
void dense_mid_kernel(const float* __restrict__ yin, const float* __restrict__ ssin,
                      const float* __restrict__ W, const float* __restrict__ bias,
                      float* __restrict__ yout,
                      float* __restrict__ psum, float* __restrict__ psq,
                      float* __restrict__ gmax, float* __restrict__ gmin) {
  constexpr int NG = 256 / CGN;
  __shared__ float xs[RPB * 68];
  __shared__ float ws[64 * COUT];
  __shared__ float scs[64], shs[64];
  __shared__ float red[2][NG][COUT];
  __shared__ float redm[MM ? 2 : 1][MM ? NG : 1][MM ? COUT : 1];
  const int blk = blockIdx.x, t = threadIdx.x;
  if (t < 64) { scs[t] = ssin[t]; shs[t] = ssin[128 + t]; }
  __syncthreads();
  const size_t rbase = (size_t)blk * RPB;
  for (int e = t; e < RPB * 64; e += 256) {
    int c = e & 63;
    float v = yin[rbase * 64 + e];
    xs[(e >> 6) * 68 + c] = fmaxf(fmaf(v, scs[c], shs[c]), 0.f);
  }
  for (int e = t; e < 64 * COUT; e += 256) ws[e] = W[e];
  __syncthreads();
  const int rg = t / CGN, cg = t % CGN;
  float acc[4][4];
  float4 bv = *(const float4*)(bias + cg * 4);
  #pragma unroll
  for (int r = 0; r < 4; r++) { acc[r][0] = bv.x; acc[r][1] = bv.y; acc[r][2] = bv.z; acc[r][3] = bv.w; }
  for (int k0 = 0; k0 < 64; k0 += 4) {
    float4 xv[4];
    #pragma unroll
    for (int r = 0; r < 4; r++)
      xv[r] = *(const float4*)(xs + (rg * 4 + r) * 68 + k0);
    #pragma unroll
    for (int kk = 0; kk < 4; kk++) {
      float4 wv = *(const float4*)(ws + (k0 + kk) * COUT + cg * 4);
      #pragma unroll
      for (int r = 0; r < 4; r++) {
        float x = (&xv[r].x)[kk];
        acc[r][0] = fmaf(x, wv.x, acc[r][0]);
        acc[r][1] = fmaf(x, wv.y, acc[r][1]);
        acc[r][2] = fmaf(x, wv.z, acc[r][2]);
        acc[r][3] = fmaf(x, wv.w, acc[r][3]);
      }
    }
  }
  if constexpr (!MM) {
    #pragma unroll
    for (int r = 0; r < 4; r++)
      *(float4*)(yout + (rbase + rg * 4 + r) * COUT + cg * 4) =
          make_float4(acc[r][0], acc[r][1], acc[r][2], acc[r][3]);
  }
  #pragma unroll
  for (int c4 = 0; c4 < 4; c4++) {
    float s = 0.f, q = 0.f;
    #pragma unroll
    for (int r = 0; r < 4; r++) { float v = acc[r][c4]; s += v; q = fmaf(v, v, q); }
    red[0][rg][cg * 4 + c4] = s;
    red[1][rg][cg * 4 + c4] = q;
    if constexpr (MM) {
      float mx = acc[0][c4], mn = acc[0][c4];
      #pragma unroll
      for (int r = 1; r < 4; r++) { mx = fmaxf(mx, acc[r][c4]); mn = fminf(mn, acc[r][c4]); }
      redm[0][rg][cg * 4 + c4] = mx;
      redm[1][rg][cg * 4 + c4] = mn;
    }
  }
  __syncthreads();
  if (t < COUT) {
    float S = 0.f, Q = 0.f;
    #pragma unroll
    for (int g = 0; g < NG; g++) { S += red[0][g][t]; Q += red[1][g][t]; }
    psum[(size_t)t * NBLKS + blk] = S;
    psq [(size_t)t * NBLKS + blk] = Q;
    if constexpr (MM) {
      float mx = redm[0][0][t], mn = redm[1][0][t];
      #pragma unroll
      for (int g = 1; g < NG; g++) { mx = fmaxf(mx, redm[0][g][t]); mn = fminf(mn, redm[1][g][t]); }
      gmax[(size_t)blk * COUT + t] = mx;
      gmin[(size_t)blk * COUT + t] = mn;
    }
  }
}

// ---------------------------------------------------------------------------
// stats finalize (unchanged)
// ---------------------------------------------------------------------------
template <int NBLK>
__global__ __launch_bounds__(256)
void stats_final_kernel(const float* __restrict__ psum, const float* __restrict__ psq,
                        const float* __restrict__ g, const float* __restrict__ be,
                        float* __restrict__ ss_out) {
  const int c = blockIdx.x, t = threadIdx.x;
  float S = 0.f, Q = 0.f;
  for (int i = t; i < NBLK; i += 256) {
    S += psum[(size_t)c * NBLK + i];
    Q += psq [(size_t)c * NBLK + i];
  }
  __shared__ float sS[256], sQ[256];
  sS[t] = S; sQ[t] = Q;
  __syncthreads();
  #pragma unroll
  for (int off = 128; off; off >>= 1) {
    if (t < off) { sS[t] += sS[t + off]; sQ[t] += sQ[t + off]; }
    __syncthreads();
  }
  if (t == 0) {
    const float inv = 1.0f / 262144.0f;
    float mean = sS[0] * inv;
    float var = sQ[0] * inv - mean * mean;
    float scale = g[c] / sqrtf(var + 1e-3f);
    ss_out[c] = scale;
    ss_out[128 + c] = be[c] - mean * scale;
  }
}

// pool finalize (unchanged)
__global__ __launch_bounds__(128)
void pool_final_kernel(const float* __restrict__ gmax, const float* __restrict__ gmin,
                       const float* __restrict__ ss2, float* __restrict__ out1) {
  const int blk = blockIdx.x, c = threadIdx.x;
  const float sc = ss2[c], sh = ss2[128 + c];
  float v = (sc >= 0.f) ? gmax[(size_t)blk * C3 + c] : gmin[(size_t)blk * C3 + c];
  out1[(size_t)blk * C3 + c] = fmaxf(fmaf(v, sc, sh), 0.f);
}

extern "C" void kernel_launch(void* const* d_in, const int* in_sizes, int n_in,
                              void* d_out, int out_size, void* d_ws, size_t ws_size,
                              hipStream_t stream) {
  const float* xyz = (const float*)d_in[0];
  const float* pts = (const float*)d_in[1];
  const float* w0 = (const float*)d_in[2];
  const float* b0 = (const float*)d_in[3];
  const float* g0 = (const float*)d_in[4];
  const float* be0 = (const float*)d_in[5];
  const float* w1 = (const float*)d_in[6];
  const float* b1 = (const float*)d_in[7];
  const float* g1 = (const float*)d_in[8];
  const float* be1 = (const float*)d_in[9];
  const float* w2 = (const float*)d_in[10];
  const float* b2 = (const float*)d_in[11];
  const float* g2 = (const float*)d_in[12];
  const float* be2 = (const float*)d_in[13];

  float* out = (float*)d_out;
  float* cent = out;                       // [8,1024,3]
  float* out1 = out + (size_t)NB * NC * 3; // [8,1024,128]

  char* ws = (char*)d_ws;
  int*   dbg  = (int*)ws;                  // ablation dump (dead)
  float* ssA  = (float*)(ws + OFF_SS);
  float* h0   = (float*)(ws + OFF_H0);
  float* y0   = (float*)(ws + OFF_Y0);
  float* y1   = (float*)(ws + OFF_Y1);
  float* psum = (float*)(ws + OFF_PSUM);
  float* psq  = (float*)(ws + OFF_PSQ);
  float* gmx  = (float*)(ws + OFF_GMX);
  float* gmn  = (float*)(ws + OFF_GMN);

  fps_kernel<<<dim3(NB), dim3(512), 0, stream>>>(xyz, cent);
  ball_kernel<<<dim3(NB * NC), dim3(256), 0, stream>>>(xyz, pts, cent, h0);

  dense0_kernel<<<dim3(ROWS_TOT / 64), dim3(256), 0, stream>>>(h0, w0, b0, y0, psum, psq);
  stats_final_kernel<4096><<<dim3(64), dim3(256), 0, stream>>>(psum, psq, g0, be0, ssA + 0 * 256);

  dense_mid_kernel<64, 64, 16, 4096, false><<<dim3(ROWS_TOT / 64), dim3(256), 0, stream>>>(
      y0, ssA + 0 * 256, w1, b1, y1, psum, psq, nullptr, nullptr);
  stats_final_kernel<4096><<<dim3(64), dim3(256), 0, stream>>>(psum, psq, g1, be1, ssA + 1 * 256);

  dense_mid_kernel<32, 128, 32, 8192, true><<<dim3(ROWS_TOT / 32), dim3(256), 0, stream>>>(
      y1, ssA + 1 * 256, w2, b2, nullptr, psum, psq, gmx, gmn);
  stats_final_kernel<8192><<<dim3(128), dim3(256), 0, stream>>>(psum, psq, g2, be2, ssA + 2 * 256);

  pool_final_kernel<<<dim3(NB * NC), dim3(128), 0, stream>>>(gmx, gmn, ssA + 2 * 256, out1);

  // --- measurement probes (dead output; x5 reps; read durations from rocprof) ---
  fps_sync_probe<<<dim3(NB), dim3(512), 0, stream>>>(xyz, dbg);
  fps_compute_probe<<<dim3(NB), dim3(512), 0, stream>>>(xyz, dbg);

  (void)in_sizes; (void)n_in; (void)out_size; (void)ws_size;
}

// Round 6
// 971.822 us; speedup vs baseline: 4.7897x; 4.7897x over previous
//
#include <hip/hip_runtime.h>

// Problem constants (B=8, N=4096, n_points=1024, n_samples=32, D_PTS=6, MLPS=[64,64,128])
#define NPTS  4096
#define NB    8
#define NC    1024
#define NSAMP 32
#define DP    6
#define C0    9      // 3 + D_PTS
#define C3    128
#define ROWS_TOT 262144   // NB*NC*NSAMP

// Workspace layout (bytes). Requires ws_size >= ~184 MB.
#define OFF_SS   (32ull<<10)     // 3 layers x {scale[128], shift[128]}
#define OFF_H0   (1ull<<20)      // h0: 262144 x 9 f32 (9.4 MB)
#define OFF_Y0   (16ull<<20)     // y0: 262144 x 64 f32 (67 MB)
#define OFF_Y1   (96ull<<20)     // y1: 262144 x 64 f32 (67 MB)
#define OFF_PSUM (168ull<<20)    // per-block channel sums   [C][NBLK] (max 4 MB)
#define OFF_PSQ  (172ull<<20)    // per-block channel sumsq  [C][NBLK] (max 4 MB)
#define OFF_GMX  (176ull<<20)    // per-centroid channel max [8192][128] (4 MB)
#define OFF_GMN  (180ull<<20)    // per-centroid channel min [8192][128] (4 MB)

typedef unsigned long long ull;

// Exact (no-FMA) squared distance to match numpy rounding; sum order ((x+y)+z).
// (still used by ball_kernel, where exactness vs the 0.04 clip matters)
__device__ __forceinline__ float sqdist_noc(float x, float y, float z,
                                            float cx, float cy, float cz) {
  #pragma clang fp contract(off)
  float dx = x - cx, dy = y - cy, dz = z - cz;
  return dx * dx + dy * dy + dz * dz;
}

// 64-bit DPP move (two 32-bit halves, same ctrl; old=self so masked lanes keep value)
template <int CTRL, int RM>
__device__ __forceinline__ ull dpp_mov_u64(ull x) {
  int lo = (int)(unsigned)(x & 0xFFFFFFFFull);
  int hi = (int)(unsigned)(x >> 32);
  int rlo = __builtin_amdgcn_update_dpp(lo, lo, CTRL, RM, 0xf, false);
  int rhi = __builtin_amdgcn_update_dpp(hi, hi, CTRL, RM, 0xf, false);
  return ((ull)(unsigned)rhi << 32) | (unsigned)rlo;
}

__device__ __forceinline__ ull umax64(ull a, ull b) { return a > b ? a : b; }

// wave64 u64 max reduce, all-VALU; result in lane 63.
__device__ __forceinline__ ull wave64_umax(ull x) {
  x = umax64(x, dpp_mov_u64<0x111, 0xf>(x));  // row_shr:1
  x = umax64(x, dpp_mov_u64<0x112, 0xf>(x));  // row_shr:2
  x = umax64(x, dpp_mov_u64<0x114, 0xf>(x));  // row_shr:4
  x = umax64(x, dpp_mov_u64<0x118, 0xf>(x));  // row_shr:8
  x = umax64(x, dpp_mov_u64<0x142, 0xa>(x));  // row_bcast:15 -> rows 1,3
  x = umax64(x, dpp_mov_u64<0x143, 0xc>(x));  // row_bcast:31 -> rows 2,3
  return x;
}

// ---------------------------------------------------------------------------
// FPS: 1023 sequential farthest-from-last steps; 512 thr, 8 pts/thread.
// ISSUE-DIET (R5 probes: compute phase 89%-VALU-issue-bound on active CUs):
// argmax |p-c|^2 == argmax (|p|^2 - 2 p.c): precompute h=|p|^2, per-step key
// = 3 FMA/pt (vs 11-inst exact sqdist). Retire by h=-INF (always loses).
// Key may be negative -> sign-flip total-order encode before u64 pack.
// Tie-break: equal f32 keys -> (4095-idx) picks smaller index (argmax-first);
// within thread strict > keeps first. Single barrier, parity LDS exchange.
// ---------------------------------------------------------------------------
__global__ __launch_bounds__(512)
void fps_kernel(const float* __restrict__ xyz, float* __restrict__ cent) {
  const int b = blockIdx.x;
  const int t = threadIdx.x;
  const float* X = xyz + (size_t)b * NPTS * 3;
  float* OC = cent + (size_t)b * NC * 3;

  __shared__ float4 sxyz[NPTS];                 // 64 KB
  __shared__ alignas(16) ull wk[2][8];
  __shared__ int sidx[NC];                      // 4 KB

  for (int p = t; p < NPTS; p += 512)
    sxyz[p] = make_float4(X[p * 3 + 0], X[p * 3 + 1], X[p * 3 + 2], 0.f);
  __syncthreads();

  float px[8], py[8], pz[8], h[8];
  #pragma unroll
  for (int i = 0; i < 8; i++) {
    float4 v = sxyz[t * 8 + i];
    px[i] = v.x; py[i] = v.y; pz[i] = v.z;
    h[i] = fmaf(v.x, v.x, fmaf(v.y, v.y, v.z * v.z));   // |p|^2
  }

  int last = 0;  // deterministic seed index 0
  for (int k = 1; k < NC; k++) {
    const int par = k & 1;
    if (t == 0) sidx[k - 1] = last;
    float4 c = sxyz[last];                      // broadcast read
    const float cx2 = -2.0f * c.x, cy2 = -2.0f * c.y, cz2 = -2.0f * c.z;
    if ((last >> 3) == t) {                     // retire: -INF loses everything
      int ii = last & 7;
      #pragma unroll
      for (int i = 0; i < 8; i++)
        if (i == ii) h[i] = -__builtin_inff();
    }

    float mx = -__builtin_inff(); int mj = 0;
    #pragma unroll
    for (int i = 0; i < 8; i++) {
      float key = fmaf(pz[i], cz2, fmaf(py[i], cy2, fmaf(px[i], cx2, h[i])));
      if (key > mx) { mx = key; mj = i; }       // strict > keeps first index
    }
    // sign-flip encode: monotone f32 -> u32 total order (handles negatives)
    unsigned mb = __float_as_uint(mx);
    mb ^= (unsigned)((int)mb >> 31) | 0x80000000u;
    ull key = ((ull)mb << 12) | (unsigned)(4095 - (t * 8 + mj));
    key = wave64_umax(key);

    if ((t & 63) == 63) wk[par][t >> 6] = key;  // leader = lane 63
    __syncthreads();
    const ulonglong2* W2 = (const ulonglong2*)&wk[par][0];
    ulonglong2 p0 = W2[0], p1 = W2[1], p2 = W2[2], p3 = W2[3];
    ull m0 = umax64(umax64(p0.x, p0.y), umax64(p1.x, p1.y));
    ull m1 = umax64(umax64(p2.x, p2.y), umax64(p3.x, p3.y));
    last = 4095 - (int)(umax64(m0, m1) & 0xFFFull);
  }
  if (t == 0) sidx[NC - 1] = last;
  __syncthreads();
  for (int i = t; i < NC; i += 512) {           // one-shot centroid emit
    float4 c = sxyz[sidx[i]];
    OC[i * 3 + 0] = c.x;
    OC[i * 3 + 1] = c.y;
    OC[i * 3 + 2] = c.z;
  }
}

// ---------------------------------------------------------------------------
// query_ball + gather + concat (unchanged from R4): exact stable-argsort
// semantics via the min(dist, r^2=0.04) quirk.
// ---------------------------------------------------------------------------
#define BCAP 256
__global__ __launch_bounds__(256)
void ball_kernel(const float* __restrict__ xyz, const float* __restrict__ pts,
                 const float* __restrict__ cent, float* __restrict__ h0) {
  const int blk = blockIdx.x;       // b*NC + c
  const int b = blk >> 10;
  const int t = threadIdx.x;
  const float* X = xyz + (size_t)b * NPTS * 3;
  const float* P = pts + (size_t)b * NPTS * DP;
  const float cx = cent[(size_t)blk * 3 + 0];
  const float cy = cent[(size_t)blk * 3 + 1];
  const float cz = cent[(size_t)blk * 3 + 2];

  __shared__ int scount;
  __shared__ ull skeys[BCAP];
  __shared__ ull ssorted[BCAP];
  __shared__ int sel[NSAMP];
  if (t == 0) scount = 0;
  __syncthreads();

  #pragma unroll
  for (int i = 0; i < 16; i++) {
    int j = t * 16 + i;
    float sq = sqdist_noc(X[j * 3 + 0], X[j * 3 + 1], X[j * 3 + 2], cx, cy, cz);
    if (sq < 0.0017f) {                       // conservative guard
      float d = (sq > 0.f) ? sqrtf(sq) : 0.f; // exact per-reference norm
      if (d < 0.04f) {                        // strictly inside the clip value
        int pos = atomicAdd(&scount, 1);
        if (pos < BCAP)
          skeys[pos] = ((ull)(unsigned)__float_as_int(d) << 12) | (unsigned)j;
      }
    }
  }
  __syncthreads();
  const int M = min(scount, BCAP);

  if (t < M) {                                // rank-sort inner set
    ull my = skeys[t];
    int r = 0;
    for (int j2 = 0; j2 < M; j2++) r += (skeys[j2] < my);
    ssorted[r] = my;
  }
  __syncthreads();

  if (t < NSAMP) {
    int v;
    if (t < M) {
      v = (int)(ssorted[t] & 0xFFFull);
    } else {
      int s = t - M;                          // s-th smallest non-inner index
      int idx = s;
      for (int it = 0; it < 40; it++) {
        int c = 0;
        for (int j2 = 0; j2 < M; j2++) c += ((int)(skeys[j2] & 0xFFFull) <= idx);
        int nidx = s + c;
        if (nidx == idx) break;
        idx = nidx;
      }
      v = idx;
    }
    sel[t] = v;
  }
  __syncthreads();

  float* H = h0 + (size_t)blk * NSAMP * C0;
  for (int e = t; e < NSAMP * C0; e += 256) {
    int k = e / C0;
    int c = e - k * C0;
    int j = sel[k];
    H[e] = (c < 3) ? X[j * 3 + c] : P[j * DP + (c - 3)];
  }
}

// ---------------------------------------------------------------------------
// dense0 (unchanged): h0 @ W[9,64] + b -> y0, fused BN partials.
// ---------------------------------------------------------------------------
__global__ __launch_bounds__(256)
void dense0_kernel(const float* __restrict__ h0, const float* __restrict__ W,
                   const float* __restrict__ bias, float* __restrict__ yout,
                   float* __restrict__ psum, float* __restrict__ psq) {
  __shared__ float xs[64 * C0];
  __shared__ float ws[C0 * 64];
  __shared__ float red[2][16][64];
  const int blk = blockIdx.x, t = threadIdx.x;
  const size_t rbase = (size_t)blk * 64;
  for (int e = t; e < 64 * C0; e += 256) xs[e] = h0[rbase * C0 + e];
  for (int e = t; e < C0 * 64; e += 256) ws[e] = W[e];
  __syncthreads();
  const int rg = t >> 4, cg = t & 15;
  float acc[4][4];
  float4 bv = *(const float4*)(bias + cg * 4);
  #pragma unroll
  for (int r = 0; r < 4; r++) { acc[r][0] = bv.x; acc[r][1] = bv.y; acc[r][2] = bv.z; acc[r][3] = bv.w; }
  #pragma unroll
  for (int k = 0; k < C0; k++) {
    float4 wv = *(const float4*)(ws + k * 64 + cg * 4);
    #pragma unroll
    for (int r = 0; r < 4; r++) {
      float x = xs[(rg * 4 + r) * C0 + k];
      acc[r][0] = fmaf(x, wv.x, acc[r][0]);
      acc[r][1] = fmaf(x, wv.y, acc[r][1]);
      acc[r][2] = fmaf(x, wv.z, acc[r][2]);
      acc[r][3] = fmaf(x, wv.w, acc[r][3]);
    }
  }
  #pragma unroll
  for (int r = 0; r < 4; r++)
    *(float4*)(yout + (rbase + rg * 4 + r) * 64 + cg * 4) =
        make_float4(acc[r][0], acc[r][1], acc[r][2], acc[r][3]);
  #pragma unroll
  for (int c4 = 0; c4 < 4; c4++) {
    float s = 0.f, q = 0.f;
    #pragma unroll
    for (int r = 0; r < 4; r++) { float v = acc[r][c4]; s += v; q = fmaf(v, v, q); }
    red[0][rg][cg * 4 + c4] = s;
    red[1][rg][cg * 4 + c4] = q;
  }
  __syncthreads();
  if (t < 64) {
    float S = 0.f, Q = 0.f;
    #pragma unroll
    for (int g = 0; g < 16; g++) { S += red[0][g][t]; Q += red[1][g][t]; }
    psum[(size_t)t * 4096 + blk] = S;
    psq [(size_t)t * 4096 + blk] = Q;
  }
}

// ---------------------------------------------------------------------------
// dense mid (unchanged)
// ---------------------------------------------------------------------------
template <int RPB, int COUT, int CGN, int NBLKS, bool MM>
__global__ __launch_bounds__(256)
void dense_mid_kernel(const float* __restrict__ yin, const float* __restrict__ ssin,
                      const float* __restrict__ W, const float* __restrict__ bias,
                      float* __restrict__ yout,
                      float* __restrict__ psum, float* __restrict__ psq,
                      float* __restrict__ gmax, float* __restrict__ gmin) {
  constexpr int NG = 256 / CGN;
  __shared__ float xs[RPB * 68];
  __shared__ float ws[64 * COUT];
  __shared__ float scs[64], shs[64];
  __shared__ float red[2][NG][COUT];
  __shared__ float redm[MM ? 2 : 1][MM ? NG : 1][MM ? COUT : 1];
  const int blk = blockIdx.x, t = threadIdx.x;
  if (t < 64) { scs[t] = ssin[t]; shs[t] = ssin[128 + t]; }
  __syncthreads();
  const size_t rbase = (size_t)blk * RPB;
  for (int e = t; e < RPB * 64; e += 256) {
    int c = e & 63;
    float v = yin[rbase * 64 + e];
    xs[(e >> 6) * 68 + c] = fmaxf(fmaf(v, scs[c], shs[c]), 0.f);
  }
  for (int e = t; e < 64 * COUT; e += 256) ws[e] = W[e];
  __syncthreads();
  const int rg = t / CGN, cg = t % CGN;
  float acc[4][4];
  float4 bv = *(const float4*)(bias + cg * 4);
  #pragma unroll
  for (int r = 0; r < 4; r++) { acc[r][0] = bv.x; acc[r][1] = bv.y; acc[r][2] = bv.z; acc[r][3] = bv.w; }
  for (int k0 = 0; k0 < 64; k0 += 4) {
    float4 xv[4];
    #pragma unroll
    for (int r = 0; r < 4; r++)
      xv[r] = *(const float4*)(xs + (rg * 4 + r) * 68 + k0);
    #pragma unroll
    for (int kk = 0; kk < 4; kk++) {
      float4 wv = *(const float4*)(ws + (k0 + kk) * COUT + cg * 4);
      #pragma unroll
      for (int r = 0; r < 4; r++) {
        float x = (&xv[r].x)[kk];
        acc[r][0] = fmaf(x, wv.x, acc[r][0]);
        acc[r][1] = fmaf(x, wv.y, acc[r][1]);
        acc[r][2] = fmaf(x, wv.z, acc[r][2]);
        acc[r][3] = fmaf(x, wv.w, acc[r][3]);
      }
    }
  }
  if constexpr (!MM) {
    #pragma unroll
    for (int r = 0; r < 4; r++)
      *(float4*)(yout + (rbase + rg * 4 + r) * COUT + cg * 4) =
          make_float4(acc[r][0], acc[r][1], acc[r][2], acc[r][3]);
  }
  #pragma unroll
  for (int c4 = 0; c4 < 4; c4++) {
    float s = 0.f, q = 0.f;
    #pragma unroll
    for (int r = 0; r < 4; r++) { float v = acc[r][c4]; s += v; q = fmaf(v, v, q); }
    red[0][rg][cg * 4 + c4] = s;
    red[1][rg][cg * 4 + c4] = q;
    if constexpr (MM) {
      float mx = acc[0][c4], mn = acc[0][c4];
      #pragma unroll
      for (int r = 1; r < 4; r++) { mx = fmaxf(mx, acc[r][c4]); mn = fminf(mn, acc[r][c4]); }
      redm[0][rg][cg * 4 + c4] = mx;
      redm[1][rg][cg * 4 + c4] = mn;
    }
  }
  __syncthreads();
  if (t < COUT) {
    float S = 0.f, Q = 0.f;
    #pragma unroll
    for (int g = 0; g < NG; g++) { S += red[0][g][t]; Q += red[1][g][t]; }
    psum[(size_t)t * NBLKS + blk] = S;
    psq [(size_t)t * NBLKS + blk] = Q;
    if constexpr (MM) {
      float mx = redm[0][0][t], mn = redm[1][0][t];
      #pragma unroll
      for (int g = 1; g < NG; g++) { mx = fmaxf(mx, redm[0][g][t]); mn = fminf(mn, redm[1][g][t]); }
      gmax[(size_t)blk * COUT + t] = mx;
      gmin[(size_t)blk * COUT + t] = mn;
    }
  }
}

// ---------------------------------------------------------------------------
// stats finalize (unchanged)
// ---------------------------------------------------------------------------
template <int NBLK>
__global__ __launch_bounds__(256)
void stats_final_kernel(const float* __restrict__ psum, const float* __restrict__ psq,
                        const float* __restrict__ g, const float* __restrict__ be,
                        float* __restrict__ ss_out) {
  const int c = blockIdx.x, t = threadIdx.x;
  float S = 0.f, Q = 0.f;
  for (int i = t; i < NBLK; i += 256) {
    S += psum[(size_t)c * NBLK + i];
    Q += psq [(size_t)c * NBLK + i];
  }
  __shared__ float sS[256], sQ[256];
  sS[t] = S; sQ[t] = Q;
  __syncthreads();
  #pragma unroll
  for (int off = 128; off; off >>= 1) {
    if (t < off) { sS[t] += sS[t + off]; sQ[t] += sQ[t + off]; }
    __syncthreads();
  }
  if (t == 0) {
    const float inv = 1.0f / 262144.0f;
    float mean = sS[0] * inv;
    float var = sQ[0] * inv - mean * mean;
    float scale = g[c] / sqrtf(var + 1e-3f);
    ss_out[c] = scale;
    ss_out[128 + c] = be[c] - mean * scale;
  }
}

// pool finalize (unchanged)
__global__ __launch_bounds__(128)
void pool_final_kernel(const float* __restrict__ gmax, const float* __restrict__ gmin,
                       const float* __restrict__ ss2, float* __restrict__ out1) {
  const int blk = blockIdx.x, c = threadIdx.x;
  const float sc = ss2[c], sh = ss2[128 + c];
  float v = (sc >= 0.f) ? gmax[(size_t)blk * C3 + c] : gmin[(size_t)blk * C3 + c];
  out1[(size_t)blk * C3 + c] = fmaxf(fmaf(v, sc, sh), 0.f);
}

extern "C" void kernel_launch(void* const* d_in, const int* in_sizes, int n_in,
                              void* d_out, int out_size, void* d_ws, size_t ws_size,
                              hipStream_t stream) {
  const float* xyz = (const float*)d_in[0];
  const float* pts = (const float*)d_in[1];
  const float* w0 = (const float*)d_in[2];
  const float* b0 = (const float*)d_in[3];
  const float* g0 = (const float*)d_in[4];
  const float* be0 = (const float*)d_in[5];
  const float* w1 = (const float*)d_in[6];
  const float* b1 = (const float*)d_in[7];
  const float* g1 = (const float*)d_in[8];
  const float* be1 = (const float*)d_in[9];
  const float* w2 = (const float*)d_in[10];
  const float* b2 = (const float*)d_in[11];
  const float* g2 = (const float*)d_in[12];
  const float* be2 = (const float*)d_in[13];

  float* out = (float*)d_out;
  float* cent = out;                       // [8,1024,3]
  float* out1 = out + (size_t)NB * NC * 3; // [8,1024,128]

  char* ws = (char*)d_ws;
  float* ssA  = (float*)(ws + OFF_SS);
  float* h0   = (float*)(ws + OFF_H0);
  float* y0   = (float*)(ws + OFF_Y0);
  float* y1   = (float*)(ws + OFF_Y1);
  float* psum = (float*)(ws + OFF_PSUM);
  float* psq  = (float*)(ws + OFF_PSQ);
  float* gmx  = (float*)(ws + OFF_GMX);
  float* gmn  = (float*)(ws + OFF_GMN);

  fps_kernel<<<dim3(NB), dim3(512), 0, stream>>>(xyz, cent);
  ball_kernel<<<dim3(NB * NC), dim3(256), 0, stream>>>(xyz, pts, cent, h0);

  dense0_kernel<<<dim3(ROWS_TOT / 64), dim3(256), 0, stream>>>(h0, w0, b0, y0, psum, psq);
  stats_final_kernel<4096><<<dim3(64), dim3(256), 0, stream>>>(psum, psq, g0, be0, ssA + 0 * 256);

  dense_mid_kernel<64, 64, 16, 4096, false><<<dim3(ROWS_TOT / 64), dim3(256), 0, stream>>>(
      y0, ssA + 0 * 256, w1, b1, y1, psum, psq, nullptr, nullptr);
  stats_final_kernel<4096><<<dim3(64), dim3(256), 0, stream>>>(psum, psq, g1, be1, ssA + 1 * 256);

  dense_mid_kernel<32, 128, 32, 8192, true><<<dim3(ROWS_TOT / 32), dim3(256), 0, stream>>>(
      y1, ssA + 1 * 256, w2, b2, nullptr, psum, psq, gmx, gmn);
  stats_final_kernel<8192><<<dim3(128), dim3(256), 0, stream>>>(psum, psq, g2, be2, ssA + 2 * 256);

  pool_final_kernel<<<dim3(NB * NC), dim3(128), 0, stream>>>(gmx, gmn, ssA + 2 * 256, out1);

  (void)in_sizes; (void)n_in; (void)out_size; (void)ws_size;
}

// Round 7
// 963.284 us; speedup vs baseline: 4.8322x; 1.0089x over previous
//
#include <hip/hip_runtime.h>

// Problem constants (B=8, N=4096, n_points=1024, n_samples=32, D_PTS=6, MLPS=[64,64,128])
#define NPTS  4096
#define NB    8
#define NC    1024
#define NSAMP 32
#define DP    6
#define C0    9      // 3 + D_PTS
#define C3    128
#define ROWS_TOT 262144   // NB*NC*NSAMP

// Workspace layout (bytes). Requires ws_size >= ~184 MB.
#define OFF_SS   (32ull<<10)     // 3 layers x {scale[128], shift[128]}
#define OFF_H0   (1ull<<20)      // h0: 262144 x 9 f32 (9.4 MB)
#define OFF_Y0   (16ull<<20)     // y0: 262144 x 64 f32 (67 MB)
#define OFF_Y1   (96ull<<20)     // y1: 262144 x 64 f32 (67 MB)
#define OFF_PSUM (168ull<<20)    // per-block channel sums   [C][NBLK] (max 4 MB)
#define OFF_PSQ  (172ull<<20)    // per-block channel sumsq  [C][NBLK] (max 4 MB)
#define OFF_GMX  (176ull<<20)    // per-centroid channel max [8192][128] (4 MB)
#define OFF_GMN  (180ull<<20)    // per-centroid channel min [8192][128] (4 MB)

typedef unsigned long long ull;

// Exact (no-FMA) squared distance to match numpy rounding; sum order ((x+y)+z).
// (used by ball_kernel, where exactness vs the 0.04 clip matters)
__device__ __forceinline__ float sqdist_noc(float x, float y, float z,
                                            float cx, float cy, float cz) {
  #pragma clang fp contract(off)
  float dx = x - cx, dy = y - cy, dz = z - cz;
  return dx * dx + dy * dy + dz * dz;
}

// 64-bit DPP move (two 32-bit halves, same ctrl; old=self so masked lanes keep value)
template <int CTRL, int RM>
__device__ __forceinline__ ull dpp_mov_u64(ull x) {
  int lo = (int)(unsigned)(x & 0xFFFFFFFFull);
  int hi = (int)(unsigned)(x >> 32);
  int rlo = __builtin_amdgcn_update_dpp(lo, lo, CTRL, RM, 0xf, false);
  int rhi = __builtin_amdgcn_update_dpp(hi, hi, CTRL, RM, 0xf, false);
  return ((ull)(unsigned)rhi << 32) | (unsigned)rlo;
}

__device__ __forceinline__ ull umax64(ull a, ull b) { return a > b ? a : b; }

// wave64 u64 max reduce, all-VALU; result in lane 63.
__device__ __forceinline__ ull wave64_umax(ull x) {
  x = umax64(x, dpp_mov_u64<0x111, 0xf>(x));  // row_shr:1
  x = umax64(x, dpp_mov_u64<0x112, 0xf>(x));  // row_shr:2
  x = umax64(x, dpp_mov_u64<0x114, 0xf>(x));  // row_shr:4
  x = umax64(x, dpp_mov_u64<0x118, 0xf>(x));  // row_shr:8
  x = umax64(x, dpp_mov_u64<0x142, 0xa>(x));  // row_bcast:15 -> rows 1,3
  x = umax64(x, dpp_mov_u64<0x143, 0xc>(x));  // row_bcast:31 -> rows 2,3
  return x;
}

// ---------------------------------------------------------------------------
// FPS: 1023 sequential farthest-from-last steps; 256 thr (4 waves), 16 pts/thr.
// R7: halve the per-SIMD replication of the wave-reduce (DPP+publish+fold is
// per-wave fixed cost; distance work per SIMD is invariant). 4-wave barrier,
// 4-key fold. Key = |p|^2 - 2 p.c (3 FMA/pt), retire via h=-INF, sign-flip
// u64 encode, tie-break smaller index. Single barrier per step.
// ---------------------------------------------------------------------------
__global__ __launch_bounds__(256)
void fps_kernel(const float* __restrict__ xyz, float* __restrict__ cent) {
  const int b = blockIdx.x;
  const int t = threadIdx.x;
  const float* X = xyz + (size_t)b * NPTS * 3;
  float* OC = cent + (size_t)b * NC * 3;

  __shared__ float4 sxyz[NPTS];                 // 64 KB
  __shared__ alignas(16) ull wk[2][4];
  __shared__ int sidx[NC];                      // 4 KB

  for (int p = t; p < NPTS; p += 256)
    sxyz[p] = make_float4(X[p * 3 + 0], X[p * 3 + 1], X[p * 3 + 2], 0.f);
  __syncthreads();

  float px[16], py[16], pz[16], h[16];
  #pragma unroll
  for (int i = 0; i < 16; i++) {
    float4 v = sxyz[t * 16 + i];
    px[i] = v.x; py[i] = v.y; pz[i] = v.z;
    h[i] = fmaf(v.x, v.x, fmaf(v.y, v.y, v.z * v.z));   // |p|^2
  }

  int last = 0;  // deterministic seed index 0
  for (int k = 1; k < NC; k++) {
    const int par = k & 1;
    if (t == 0) sidx[k - 1] = last;
    float4 c = sxyz[last];                      // broadcast read
    const float cx2 = -2.0f * c.x, cy2 = -2.0f * c.y, cz2 = -2.0f * c.z;
    if ((last >> 4) == t) {                     // retire: -INF loses everything
      int ii = last & 15;
      #pragma unroll
      for (int i = 0; i < 16; i++)
        if (i == ii) h[i] = -__builtin_inff();
    }

    float mx = -__builtin_inff(); int mj = 0;
    #pragma unroll
    for (int i = 0; i < 16; i++) {
      float key = fmaf(pz[i], cz2, fmaf(py[i], cy2, fmaf(px[i], cx2, h[i])));
      if (key > mx) { mx = key; mj = i; }       // strict > keeps first index
    }
    // sign-flip encode: monotone f32 -> u32 total order (handles negatives)
    unsigned mb = __float_as_uint(mx);
    mb ^= (unsigned)((int)mb >> 31) | 0x80000000u;
    ull key = ((ull)mb << 12) | (unsigned)(4095 - (t * 16 + mj));
    key = wave64_umax(key);

    if ((t & 63) == 63) wk[par][t >> 6] = key;  // leader = lane 63
    __syncthreads();
    const ulonglong2* W2 = (const ulonglong2*)&wk[par][0];
    ulonglong2 p0 = W2[0], p1 = W2[1];
    last = 4095 - (int)(umax64(umax64(p0.x, p0.y), umax64(p1.x, p1.y)) & 0xFFFull);
  }
  if (t == 0) sidx[NC - 1] = last;
  __syncthreads();
  for (int i = t; i < NC; i += 256) {           // one-shot centroid emit
    float4 c = sxyz[sidx[i]];
    OC[i * 3 + 0] = c.x;
    OC[i * 3 + 1] = c.y;
    OC[i * 3 + 2] = c.z;
  }
}

// ---------------------------------------------------------------------------
// query_ball + gather + concat (unchanged): exact stable-argsort semantics
// via the min(dist, r^2=0.04) quirk.
// ---------------------------------------------------------------------------
#define BCAP 256
__global__ __launch_bounds__(256)
void ball_kernel(const float* __restrict__ xyz, const float* __restrict__ pts,
                 const float* __restrict__ cent, float* __restrict__ h0) {
  const int blk = blockIdx.x;       // b*NC + c
  const int b = blk >> 10;
  const int t = threadIdx.x;
  const float* X = xyz + (size_t)b * NPTS * 3;
  const float* P = pts + (size_t)b * NPTS * DP;
  const float cx = cent[(size_t)blk * 3 + 0];
  const float cy = cent[(size_t)blk * 3 + 1];
  const float cz = cent[(size_t)blk * 3 + 2];

  __shared__ int scount;
  __shared__ ull skeys[BCAP];
  __shared__ ull ssorted[BCAP];
  __shared__ int sel[NSAMP];
  if (t == 0) scount = 0;
  __syncthreads();

  #pragma unroll
  for (int i = 0; i < 16; i++) {
    int j = t * 16 + i;
    float sq = sqdist_noc(X[j * 3 + 0], X[j * 3 + 1], X[j * 3 + 2], cx, cy, cz);
    if (sq < 0.0017f) {                       // conservative guard
      float d = (sq > 0.f) ? sqrtf(sq) : 0.f; // exact per-reference norm
      if (d < 0.04f) {                        // strictly inside the clip value
        int pos = atomicAdd(&scount, 1);
        if (pos < BCAP)
          skeys[pos] = ((ull)(unsigned)__float_as_int(d) << 12) | (unsigned)j;
      }
    }
  }
  __syncthreads();
  const int M = min(scount, BCAP);

  if (t < M) {                                // rank-sort inner set
    ull my = skeys[t];
    int r = 0;
    for (int j2 = 0; j2 < M; j2++) r += (skeys[j2] < my);
    ssorted[r] = my;
  }
  __syncthreads();

  if (t < NSAMP) {
    int v;
    if (t < M) {
      v = (int)(ssorted[t] & 0xFFFull);
    } else {
      int s = t - M;                          // s-th smallest non-inner index
      int idx = s;
      for (int it = 0; it < 40; it++) {
        int c = 0;
        for (int j2 = 0; j2 < M; j2++) c += ((int)(skeys[j2] & 0xFFFull) <= idx);
        int nidx = s + c;
        if (nidx == idx) break;
        idx = nidx;
      }
      v = idx;
    }
    sel[t] = v;
  }
  __syncthreads();

  float* H = h0 + (size_t)blk * NSAMP * C0;
  for (int e = t; e < NSAMP * C0; e += 256) {
    int k = e / C0;
    int c = e - k * C0;
    int j = sel[k];
    H[e] = (c < 3) ? X[j * 3 + c] : P[j * DP + (c - 3)];
  }
}

// ---------------------------------------------------------------------------
// dense0 (unchanged): h0 @ W[9,64] + b -> y0, fused BN partials.
// ---------------------------------------------------------------------------
__global__ __launch_bounds__(256)
void dense0_kernel(const float* __restrict__ h0, const float* __restrict__ W,
                   const float* __restrict__ bias, float* __restrict__ yout,
                   float* __restrict__ psum, float* __restrict__ psq) {
  __shared__ float xs[64 * C0];
  __shared__ float ws[C0 * 64];
  __shared__ float red[2][16][64];
  const int blk = blockIdx.x, t = threadIdx.x;
  const size_t rbase = (size_t)blk * 64;
  for (int e = t; e < 64 * C0; e += 256) xs[e] = h0[rbase * C0 + e];
  for (int e = t; e < C0 * 64; e += 256) ws[e] = W[e];
  __syncthreads();
  const int rg = t >> 4, cg = t & 15;
  float acc[4][4];
  float4 bv = *(const float4*)(bias + cg * 4);
  #pragma unroll
  for (int r = 0; r < 4; r++) { acc[r][0] = bv.x; acc[r][1] = bv.y; acc[r][2] = bv.z; acc[r][3] = bv.w; }
  #pragma unroll
  for (int k = 0; k < C0; k++) {
    float4 wv = *(const float4*)(ws + k * 64 + cg * 4);
    #pragma unroll
    for (int r = 0; r < 4; r++) {
      float x = xs[(rg * 4 + r) * C0 + k];
      acc[r][0] = fmaf(x, wv.x, acc[r][0]);
      acc[r][1] = fmaf(x, wv.y, acc[r][1]);
      acc[r][2] = fmaf(x, wv.z, acc[r][2]);
      acc[r][3] = fmaf(x, wv.w, acc[r][3]);
    }
  }
  #pragma unroll
  for (int r = 0; r < 4; r++)
    *(float4*)(yout + (rbase + rg * 4 + r) * 64 + cg * 4) =
        make_float4(acc[r][0], acc[r][1], acc[r][2], acc[r][3]);
  #pragma unroll
  for (int c4 = 0; c4 < 4; c4++) {
    float s = 0.f, q = 0.f;
    #pragma unroll
    for (int r = 0; r < 4; r++) { float v = acc[r][c4]; s += v; q = fmaf(v, v, q); }
    red[0][rg][cg * 4 + c4] = s;
    red[1][rg][cg * 4 + c4] = q;
  }
  __syncthreads();
  if (t < 64) {
    float S = 0.f, Q = 0.f;
    #pragma unroll
    for (int g = 0; g < 16; g++) { S += red[0][g][t]; Q += red[1][g][t]; }
    psum[(size_t)t * 4096 + blk] = S;
    psq [(size_t)t * 4096 + blk] = Q;
  }
}

// ---------------------------------------------------------------------------
// dense mid (unchanged)
// ---------------------------------------------------------------------------
template <int RPB, int COUT, int CGN, int NBLKS, bool MM>
__global__ __launch_bounds__(256)
void dense_mid_kernel(const float* __restrict__ yin, const float* __restrict__ ssin,
                      const float* __restrict__ W, const float* __restrict__ bias,
                      float* __restrict__ yout,
                      float* __restrict__ psum, float* __restrict__ psq,
                      float* __restrict__ gmax, float* __restrict__ gmin) {
  constexpr int NG = 256 / CGN;
  __shared__ float xs[RPB * 68];
  __shared__ float ws[64 * COUT];
  __shared__ float scs[64], shs[64];
  __shared__ float red[2][NG][COUT];
  __shared__ float redm[MM ? 2 : 1][MM ? NG : 1][MM ? COUT : 1];
  const int blk = blockIdx.x, t = threadIdx.x;
  if (t < 64) { scs[t] = ssin[t]; shs[t] = ssin[128 + t]; }
  __syncthreads();
  const size_t rbase = (size_t)blk * RPB;
  for (int e = t; e < RPB * 64; e += 256) {
    int c = e & 63;
    float v = yin[rbase * 64 + e];
    xs[(e >> 6) * 68 + c] = fmaxf(fmaf(v, scs[c], shs[c]), 0.f);
  }
  for (int e = t; e < 64 * COUT; e += 256) ws[e] = W[e];
  __syncthreads();
  const int rg = t / CGN, cg = t % CGN;
  float acc[4][4];
  float4 bv = *(const float4*)(bias + cg * 4);
  #pragma unroll
  for (int r = 0; r < 4; r++) { acc[r][0] = bv.x; acc[r][1] = bv.y; acc[r][2] = bv.z; acc[r][3] = bv.w; }
  for (int k0 = 0; k0 < 64; k0 += 4) {
    float4 xv[4];
    #pragma unroll
    for (int r = 0; r < 4; r++)
      xv[r] = *(const float4*)(xs + (rg * 4 + r) * 68 + k0);
    #pragma unroll
    for (int kk = 0; kk < 4; kk++) {
      float4 wv = *(const float4*)(ws + (k0 + kk) * COUT + cg * 4);
      #pragma unroll
      for (int r = 0; r < 4; r++) {
        float x = (&xv[r].x)[kk];
        acc[r][0] = fmaf(x, wv.x, acc[r][0]);
        acc[r][1] = fmaf(x, wv.y, acc[r][1]);
        acc[r][2] = fmaf(x, wv.z, acc[r][2]);
        acc[r][3] = fmaf(x, wv.w, acc[r][3]);
      }
    }
  }
  if constexpr (!MM) {
    #pragma unroll
    for (int r = 0; r < 4; r++)
      *(float4*)(yout + (rbase + rg * 4 + r) * COUT + cg * 4) =
          make_float4(acc[r][0], acc[r][1], acc[r][2], acc[r][3]);
  }
  #pragma unroll
  for (int c4 = 0; c4 < 4; c4++) {
    float s = 0.f, q = 0.f;
    #pragma unroll
    for (int r = 0; r < 4; r++) { float v = acc[r][c4]; s += v; q = fmaf(v, v, q); }
    red[0][rg][cg * 4 + c4] = s;
    red[1][rg][cg * 4 + c4] = q;
    if constexpr (MM) {
      float mx = acc[0][c4], mn = acc[0][c4];
      #pragma unroll
      for (int r = 1; r < 4; r++) { mx = fmaxf(mx, acc[r][c4]); mn = fminf(mn, acc[r][c4]); }
      redm[0][rg][cg * 4 + c4] = mx;
      redm[1][rg][cg * 4 + c4] = mn;
    }
  }
  __syncthreads();
  if (t < COUT) {
    float S = 0.f, Q = 0.f;
    #pragma unroll
    for (int g = 0; g < NG; g++) { S += red[0][g][t]; Q += red[1][g][t]; }
    psum[(size_t)t * NBLKS + blk] = S;
    psq [(size_t)t * NBLKS + blk] = Q;
    if constexpr (MM) {
      float mx = redm[0][0][t], mn = redm[1][0][t];
      #pragma unroll
      for (int g = 1; g < NG; g++) { mx = fmaxf(mx, redm[0][g][t]); mn = fminf(mn, redm[1][g][t]); }
      gmax[(size_t)blk * COUT + t] = mx;
      gmin[(size_t)blk * COUT + t] = mn;
    }
  }
}

// ---------------------------------------------------------------------------
// stats finalize (unchanged)
// ---------------------------------------------------------------------------
template <int NBLK>
__global__ __launch_bounds__(256)
void stats_final_kernel(const float* __restrict__ psum, const float* __restrict__ psq,
                        const float* __restrict__ g, const float* __restrict__ be,
                        float* __restrict__ ss_out) {
  const int c = blockIdx.x, t = threadIdx.x;
  float S = 0.f, Q = 0.f;
  for (int i = t; i < NBLK; i += 256) {
    S += psum[(size_t)c * NBLK + i];
    Q += psq [(size_t)c * NBLK + i];
  }
  __shared__ float sS[256], sQ[256];
  sS[t] = S; sQ[t] = Q;
  __syncthreads();
  #pragma unroll
  for (int off = 128; off; off >>= 1) {
    if (t < off) { sS[t] += sS[t + off]; sQ[t] += sQ[t + off]; }
    __syncthreads();
  }
  if (t == 0) {
    const float inv = 1.0f / 262144.0f;
    float mean = sS[0] * inv;
    float var = sQ[0] * inv - mean * mean;
    float scale = g[c] / sqrtf(var + 1e-3f);
    ss_out[c] = scale;
    ss_out[128 + c] = be[c] - mean * scale;
  }
}

// pool finalize (unchanged)
__global__ __launch_bounds__(128)
void pool_final_kernel(const float* __restrict__ gmax, const float* __restrict__ gmin,
                       const float* __restrict__ ss2, float* __restrict__ out1) {
  const int blk = blockIdx.x, c = threadIdx.x;
  const float sc = ss2[c], sh = ss2[128 + c];
  float v = (sc >= 0.f) ? gmax[(size_t)blk * C3 + c] : gmin[(size_t)blk * C3 + c];
  out1[(size_t)blk * C3 + c] = fmaxf(fmaf(v, sc, sh), 0.f);
}

extern "C" void kernel_launch(void* const* d_in, const int* in_sizes, int n_in,
                              void* d_out, int out_size, void* d_ws, size_t ws_size,
                              hipStream_t stream) {
  const float* xyz = (const float*)d_in[0];
  const float* pts = (const float*)d_in[1];
  const float* w0 = (const float*)d_in[2];
  const float* b0 = (const float*)d_in[3];
  const float* g0 = (const float*)d_in[4];
  const float* be0 = (const float*)d_in[5];
  const float* w1 = (const float*)d_in[6];
  const float* b1 = (const float*)d_in[7];
  const float* g1 = (const float*)d_in[8];
  const float* be1 = (const float*)d_in[9];
  const float* w2 = (const float*)d_in[10];
  const float* b2 = (const float*)d_in[11];
  const float* g2 = (const float*)d_in[12];
  const float* be2 = (const float*)d_in[13];

  float* out = (float*)d_out;
  float* cent = out;                       // [8,1024,3]
  float* out1 = out + (size_t)NB * NC * 3; // [8,1024,128]

  char* ws = (char*)d_ws;
  float* ssA  = (float*)(ws + OFF_SS);
  float* h0   = (float*)(ws + OFF_H0);
  float* y0   = (float*)(ws + OFF_Y0);
  float* y1   = (float*)(ws + OFF_Y1);
  float* psum = (float*)(ws + OFF_PSUM);
  float* psq  = (float*)(ws + OFF_PSQ);
  float* gmx  = (float*)(ws + OFF_GMX);
  float* gmn  = (float*)(ws + OFF_GMN);

  fps_kernel<<<dim3(NB), dim3(256), 0, stream>>>(xyz, cent);
  ball_kernel<<<dim3(NB * NC), dim3(256), 0, stream>>>(xyz, pts, cent, h0);

  dense0_kernel<<<dim3(ROWS_TOT / 64), dim3(256), 0, stream>>>(h0, w0, b0, y0, psum, psq);
  stats_final_kernel<4096><<<dim3(64), dim3(256), 0, stream>>>(psum, psq, g0, be0, ssA + 0 * 256);

  dense_mid_kernel<64, 64, 16, 4096, false><<<dim3(ROWS_TOT / 64), dim3(256), 0, stream>>>(
      y0, ssA + 0 * 256, w1, b1, y1, psum, psq, nullptr, nullptr);
  stats_final_kernel<4096><<<dim3(64), dim3(256), 0, stream>>>(psum, psq, g1, be1, ssA + 1 * 256);

  dense_mid_kernel<32, 128, 32, 8192, true><<<dim3(ROWS_TOT / 32), dim3(256), 0, stream>>>(
      y1, ssA + 1 * 256, w2, b2, nullptr, psum, psq, gmx, gmn);
  stats_final_kernel<8192><<<dim3(128), dim3(256), 0, stream>>>(psum, psq, g2, be2, ssA + 2 * 256);

  pool_final_kernel<<<dim3(NB * NC), dim3(128), 0, stream>>>(gmx, gmn, ssA + 2 * 256, out1);

  (void)in_sizes; (void)n_in; (void)out_size; (void)ws_size;
}

// Round 8
// 885.317 us; speedup vs baseline: 5.2577x; 1.0881x over previous
//
#include <hip/hip_runtime.h>

// Problem constants (B=8, N=4096, n_points=1024, n_samples=32, D_PTS=6, MLPS=[64,64,128])
#define NPTS  4096
#define NB    8
#define NC    1024
#define NSAMP 32
#define DP    6
#define C0    9      // 3 + D_PTS
#define C3    128
#define ROWS_TOT 262144   // NB*NC*NSAMP

// Workspace layout (bytes). Requires ws_size >= ~184 MB.
#define OFF_SS   (32ull<<10)     // 3 layers x {scale[128], shift[128]}
#define OFF_H0   (1ull<<20)      // h0: 262144 x 9 f32 (9.4 MB)
#define OFF_Y0   (16ull<<20)     // y0: 262144 x 64 f32 (67 MB)
#define OFF_Y1   (96ull<<20)     // y1: 262144 x 64 f32 (67 MB)
#define OFF_PSUM (168ull<<20)    // per-block channel sums   [C][NBLK] (max 4 MB)
#define OFF_PSQ  (172ull<<20)    // per-block channel sumsq  [C][NBLK] (max 4 MB)
#define OFF_GMX  (176ull<<20)    // per-centroid channel max [8192][128] (4 MB)
#define OFF_GMN  (180ull<<20)    // per-centroid channel min [8192][128] (4 MB)

typedef unsigned long long ull;

// Exact (no-FMA) squared distance to match numpy rounding; sum order ((x+y)+z).
// (used by ball_kernel, where exactness vs the 0.04 clip matters)
__device__ __forceinline__ float sqdist_noc(float x, float y, float z,
                                            float cx, float cy, float cz) {
  #pragma clang fp contract(off)
  float dx = x - cx, dy = y - cy, dz = z - cz;
  return dx * dx + dy * dy + dz * dz;
}

// DPP move with old=self (masked/invalid lanes keep their value -> fmax identity)
template <int CTRL, int RM>
__device__ __forceinline__ float dpp_mov_f(float x) {
  int xi = __float_as_int(x);
  int r = __builtin_amdgcn_update_dpp(xi, xi, CTRL, RM, 0xf, false);
  return __int_as_float(r);
}

// Canonical gfx9 wave64 f32 max reduce; result valid in lane 63. (validated R3)
__device__ __forceinline__ float wave64_fmax(float x) {
  x = fmaxf(x, dpp_mov_f<0x111, 0xf>(x));  // row_shr:1
  x = fmaxf(x, dpp_mov_f<0x112, 0xf>(x));  // row_shr:2
  x = fmaxf(x, dpp_mov_f<0x114, 0xf>(x));  // row_shr:4
  x = fmaxf(x, dpp_mov_f<0x118, 0xf>(x));  // row_shr:8
  x = fmaxf(x, dpp_mov_f<0x142, 0xa>(x));  // row_bcast:15 -> rows 1,3
  x = fmaxf(x, dpp_mov_f<0x143, 0xc>(x));  // row_bcast:31 -> rows 2,3
  return x;
}

// ---------------------------------------------------------------------------
// FPS: 1023 sequential farthest-from-last steps; 256 thr (4 waves), 16 pts/thr.
// R8 chain surgery (R7 showed latency-chain-bound at 1 wave/SIMD):
//  - winners publish (x,y,z,key)+gidx; fold reads 4 candidate float4s
//    (broadcast, issued together) and selects via cndmask -> the dependent
//    sxyz[last] read is OFF the chain.
//  - winner coords come from a speculative sxyz[t*16+mj] read issued BEFORE
//    the wave reduce (latency hidden under DPP+readlane).
//  - tree argmax (depth 4, strict >, low-index side first == linear first-max).
//  - f32 DPP max reduce + readlane + predicated winner write (replaces u64).
// Tie semantics: within-thread and across-waves keep first/smallest; across
// lanes in a wave, exact-f32-equal keys resolve by lane order (measure-zero).
// ---------------------------------------------------------------------------
__global__ __launch_bounds__(256)
void fps_kernel(const float* __restrict__ xyz, float* __restrict__ cent) {
  const int b = blockIdx.x;
  const int t = threadIdx.x;
  const float* X = xyz + (size_t)b * NPTS * 3;
  float* OC = cent + (size_t)b * NC * 3;

  __shared__ float4 sxyz[NPTS];                 // 64 KB
  __shared__ float4 wkc[2][4];                  // per-wave (x,y,z,key), parity-dbuf
  __shared__ alignas(16) int wki[2][4];         // per-wave winner gidx
  __shared__ int sidx[NC];                      // 4 KB

  for (int p = t; p < NPTS; p += 256)
    sxyz[p] = make_float4(X[p * 3 + 0], X[p * 3 + 1], X[p * 3 + 2], 0.f);
  __syncthreads();

  float px[16], py[16], pz[16], h[16];
  #pragma unroll
  for (int i = 0; i < 16; i++) {
    float4 v = sxyz[t * 16 + i];
    px[i] = v.x; py[i] = v.y; pz[i] = v.z;
    h[i] = fmaf(v.x, v.x, fmaf(v.y, v.y, v.z * v.z));   // |p|^2
  }

  const int wv = t >> 6;
  float4 c;   // current centroid (x,y,z,*)

  // compute candidates for the current centroid c and publish into parity pw_
  auto step_body = [&](int pw_) {
    const float c2x = c.x + c.x, c2y = c.y + c.y, c2z = c.z + c.z;
    float key[16]; int idx[16];
    #pragma unroll
    for (int i = 0; i < 16; i++) {
      // |p|^2 - 2 p.c  (neg via free VOP3 modifier)
      key[i] = fmaf(pz[i], -c2z, fmaf(py[i], -c2y, fmaf(px[i], -c2x, h[i])));
      idx[i] = i;
    }
    // tree argmax, strict > (low-index side wins ties == linear first-max)
    #pragma unroll
    for (int s = 1; s < 16; s <<= 1) {
      #pragma unroll
      for (int i = 0; i < 16; i += 2 * s) {
        bool tk = key[i + s] > key[i];
        key[i] = tk ? key[i + s] : key[i];
        idx[i] = tk ? idx[i + s] : idx[i];
      }
    }
    const float mx = key[0];
    const int mj = idx[0];
    float4 cand = sxyz[(t << 4) + mj];          // speculative; hides under reduce
    float wm = wave64_fmax(mx);
    float smax = __int_as_float(__builtin_amdgcn_readlane(__float_as_int(wm), 63));
    if (mx == smax) {                           // winner lane(s) of this wave
      wkc[pw_][wv] = make_float4(cand.x, cand.y, cand.z, smax);
      wki[pw_][wv] = (t << 4) + mj;
    }
  };

  // fold parity pr_: pick best of 4 wave candidates (first wave wins ties),
  // set c, return winning gidx
  auto fold = [&](int pr_) -> int {
    float4 q0 = wkc[pr_][0], q1 = wkc[pr_][1];
    float4 q2 = wkc[pr_][2], q3 = wkc[pr_][3];
    const int4 ii = *(const int4*)&wki[pr_][0];
    bool g1 = q1.w > q0.w; float4 ca = g1 ? q1 : q0; int ia = g1 ? ii.y : ii.x;
    bool g3 = q3.w > q2.w; float4 cb = g3 ? q3 : q2; int ib = g3 ? ii.w : ii.z;
    bool gb = cb.w > ca.w; c = gb ? cb : ca; return gb ? ib : ia;
  };

  // ---- iteration 1: selection 0 is point 0 (seed) ----
  if (t == 0) { sidx[0] = 0; h[0] = -__builtin_inff(); }   // retire point 0
  c = sxyz[0];
  step_body(1);                                 // publish par = 1&1
  __syncthreads();

  for (int k = 2; k < NC; k++) {
    const int pr = (k - 1) & 1, pw = k & 1;
    int gidx = fold(pr);                        // selection k-1
    if (t == 0) sidx[k - 1] = gidx;
    if ((gidx >> 4) == t) {                     // retire: -INF loses everything
      int m = gidx & 15;
      #pragma unroll
      for (int i = 0; i < 16; i++)
        if (i == m) h[i] = -__builtin_inff();
    }
    step_body(pw);
    __syncthreads();
  }
  {                                             // epilogue: selection 1023
    int gidx = fold(1023 & 1);
    if (t == 0) sidx[NC - 1] = gidx;
  }
  __syncthreads();
  for (int i = t; i < NC; i += 256) {           // one-shot centroid emit
    float4 cc = sxyz[sidx[i]];
    OC[i * 3 + 0] = cc.x;
    OC[i * 3 + 1] = cc.y;
    OC[i * 3 + 2] = cc.z;
  }
}

// ---------------------------------------------------------------------------
// query_ball + gather + concat (unchanged): exact stable-argsort semantics
// via the min(dist, r^2=0.04) quirk.
// ---------------------------------------------------------------------------
#define BCAP 256
__global__ __launch_bounds__(256)
void ball_kernel(const float* __restrict__ xyz, const float* __restrict__ pts,
                 const float* __restrict__ cent, float* __restrict__ h0) {
  const int blk = blockIdx.x;       // b*NC + c
  const int b = blk >> 10;
  const int t = threadIdx.x;
  const float* X = xyz + (size_t)b * NPTS * 3;
  const float* P = pts + (size_t)b * NPTS * DP;
  const float cx = cent[(size_t)blk * 3 + 0];
  const float cy = cent[(size_t)blk * 3 + 1];
  const float cz = cent[(size_t)blk * 3 + 2];

  __shared__ int scount;
  __shared__ ull skeys[BCAP];
  __shared__ ull ssorted[BCAP];
  __shared__ int sel[NSAMP];
  if (t == 0) scount = 0;
  __syncthreads();

  #pragma unroll
  for (int i = 0; i < 16; i++) {
    int j = t * 16 + i;
    float sq = sqdist_noc(X[j * 3 + 0], X[j * 3 + 1], X[j * 3 + 2], cx, cy, cz);
    if (sq < 0.0017f) {                       // conservative guard
      float d = (sq > 0.f) ? sqrtf(sq) : 0.f; // exact per-reference norm
      if (d < 0.04f) {                        // strictly inside the clip value
        int pos = atomicAdd(&scount, 1);
        if (pos < BCAP)
          skeys[pos] = ((ull)(unsigned)__float_as_int(d) << 12) | (unsigned)j;
      }
    }
  }
  __syncthreads();
  const int M = min(scount, BCAP);

  if (t < M) {                                // rank-sort inner set
    ull my = skeys[t];
    int r = 0;
    for (int j2 = 0; j2 < M; j2++) r += (skeys[j2] < my);
    ssorted[r] = my;
  }
  __syncthreads();

  if (t < NSAMP) {
    int v;
    if (t < M) {
      v = (int)(ssorted[t] & 0xFFFull);
    } else {
      int s = t - M;                          // s-th smallest non-inner index
      int idx = s;
      for (int it = 0; it < 40; it++) {
        int c = 0;
        for (int j2 = 0; j2 < M; j2++) c += ((int)(skeys[j2] & 0xFFFull) <= idx);
        int nidx = s + c;
        if (nidx == idx) break;
        idx = nidx;
      }
      v = idx;
    }
    sel[t] = v;
  }
  __syncthreads();

  float* H = h0 + (size_t)blk * NSAMP * C0;
  for (int e = t; e < NSAMP * C0; e += 256) {
    int k = e / C0;
    int c = e - k * C0;
    int j = sel[k];
    H[e] = (c < 3) ? X[j * 3 + c] : P[j * DP + (c - 3)];
  }
}

// ---------------------------------------------------------------------------
// dense0 (unchanged): h0 @ W[9,64] + b -> y0, fused BN partials.
// ---------------------------------------------------------------------------
__global__ __launch_bounds__(256)
void dense0_kernel(const float* __restrict__ h0, const float* __restrict__ W,
                   const float* __restrict__ bias, float* __restrict__ yout,
                   float* __restrict__ psum, float* __restrict__ psq) {
  __shared__ float xs[64 * C0];
  __shared__ float ws[C0 * 64];
  __shared__ float red[2][16][64];
  const int blk = blockIdx.x, t = threadIdx.x;
  const size_t rbase = (size_t)blk * 64;
  for (int e = t; e < 64 * C0; e += 256) xs[e] = h0[rbase * C0 + e];
  for (int e = t; e < C0 * 64; e += 256) ws[e] = W[e];
  __syncthreads();
  const int rg = t >> 4, cg = t & 15;
  float acc[4][4];
  float4 bv = *(const float4*)(bias + cg * 4);
  #pragma unroll
  for (int r = 0; r < 4; r++) { acc[r][0] = bv.x; acc[r][1] = bv.y; acc[r][2] = bv.z; acc[r][3] = bv.w; }
  #pragma unroll
  for (int k = 0; k < C0; k++) {
    float4 wv = *(const float4*)(ws + k * 64 + cg * 4);
    #pragma unroll
    for (int r = 0; r < 4; r++) {
      float x = xs[(rg * 4 + r) * C0 + k];
      acc[r][0] = fmaf(x, wv.x, acc[r][0]);
      acc[r][1] = fmaf(x, wv.y, acc[r][1]);
      acc[r][2] = fmaf(x, wv.z, acc[r][2]);
      acc[r][3] = fmaf(x, wv.w, acc[r][3]);
    }
  }
  #pragma unroll
  for (int r = 0; r < 4; r++)
    *(float4*)(yout + (rbase + rg * 4 + r) * 64 + cg * 4) =
        make_float4(acc[r][0], acc[r][1], acc[r][2], acc[r][3]);
  #pragma unroll
  for (int c4 = 0; c4 < 4; c4++) {
    float s = 0.f, q = 0.f;
    #pragma unroll
    for (int r = 0; r < 4; r++) { float v = acc[r][c4]; s += v; q = fmaf(v, v, q); }
    red[0][rg][cg * 4 + c4] = s;
    red[1][rg][cg * 4 + c4] = q;
  }
  __syncthreads();
  if (t < 64) {
    float S = 0.f, Q = 0.f;
    #pragma unroll
    for (int g = 0; g < 16; g++) { S += red[0][g][t]; Q += red[1][g][t]; }
    psum[(size_t)t * 4096 + blk] = S;
    psq [(size_t)t * 4096 + blk] = Q;
  }
}

// ---------------------------------------------------------------------------
// dense mid (unchanged)
// ---------------------------------------------------------------------------
template <int RPB, int COUT, int CGN, int NBLKS, bool MM>
__global__ __launch_bounds__(256)
void dense_mid_kernel(const float* __restrict__ yin, const float* __restrict__ ssin,
                      const float* __restrict__ W, const float* __restrict__ bias,
                      float* __restrict__ yout,
                      float* __restrict__ psum, float* __restrict__ psq,
                      float* __restrict__ gmax, float* __restrict__ gmin) {
  constexpr int NG = 256 / CGN;
  __shared__ float xs[RPB * 68];
  __shared__ float ws[64 * COUT];
  __shared__ float scs[64], shs[64];
  __shared__ float red[2][NG][COUT];
  __shared__ float redm[MM ? 2 : 1][MM ? NG : 1][MM ? COUT : 1];
  const int blk = blockIdx.x, t = threadIdx.x;
  if (t < 64) { scs[t] = ssin[t]; shs[t] = ssin[128 + t]; }
  __syncthreads();
  const size_t rbase = (size_t)blk * RPB;
  for (int e = t; e < RPB * 64; e += 256) {
    int c = e & 63;
    float v = yin[rbase * 64 + e];
    xs[(e >> 6) * 68 + c] = fmaxf(fmaf(v, scs[c], shs[c]), 0.f);
  }
  for (int e = t; e < 64 * COUT; e += 256) ws[e] = W[e];
  __syncthreads();
  const int rg = t / CGN, cg = t % CGN;
  float acc[4][4];
  float4 bv = *(const float4*)(bias + cg * 4);
  #pragma unroll
  for (int r = 0; r < 4; r++) { acc[r][0] = bv.x; acc[r][1] = bv.y; acc[r][2] = bv.z; acc[r][3] = bv.w; }
  for (int k0 = 0; k0 < 64; k0 += 4) {
    float4 xv[4];
    #pragma unroll
    for (int r = 0; r < 4; r++)
      xv[r] = *(const float4*)(xs + (rg * 4 + r) * 68 + k0);
    #pragma unroll
    for (int kk = 0; kk < 4; kk++) {
      float4 wv = *(const float4*)(ws + (k0 + kk) * COUT + cg * 4);
      #pragma unroll
      for (int r = 0; r < 4; r++) {
        float x = (&xv[r].x)[kk];
        acc[r][0] = fmaf(x, wv.x, acc[r][0]);
        acc[r][1] = fmaf(x, wv.y, acc[r][1]);
        acc[r][2] = fmaf(x, wv.z, acc[r][2]);
        acc[r][3] = fmaf(x, wv.w, acc[r][3]);
      }
    }
  }
  if constexpr (!MM) {
    #pragma unroll
    for (int r = 0; r < 4; r++)
      *(float4*)(yout + (rbase + rg * 4 + r) * COUT + cg * 4) =
          make_float4(acc[r][0], acc[r][1], acc[r][2], acc[r][3]);
  }
  #pragma unroll
  for (int c4 = 0; c4 < 4; c4++) {
    float s = 0.f, q = 0.f;
    #pragma unroll
    for (int r = 0; r < 4; r++) { float v = acc[r][c4]; s += v; q = fmaf(v, v, q); }
    red[0][rg][cg * 4 + c4] = s;
    red[1][rg][cg * 4 + c4] = q;
    if constexpr (MM) {
      float mx = acc[0][c4], mn = acc[0][c4];
      #pragma unroll
      for (int r = 1; r < 4; r++) { mx = fmaxf(mx, acc[r][c4]); mn = fminf(mn, acc[r][c4]); }
      redm[0][rg][cg * 4 + c4] = mx;
      redm[1][rg][cg * 4 + c4] = mn;
    }
  }
  __syncthreads();
  if (t < COUT) {
    float S = 0.f, Q = 0.f;
    #pragma unroll
    for (int g = 0; g < NG; g++) { S += red[0][g][t]; Q += red[1][g][t]; }
    psum[(size_t)t * NBLKS + blk] = S;
    psq [(size_t)t * NBLKS + blk] = Q;
    if constexpr (MM) {
      float mx = redm[0][0][t], mn = redm[1][0][t];
      #pragma unroll
      for (int g = 1; g < NG; g++) { mx = fmaxf(mx, redm[0][g][t]); mn = fminf(mn, redm[1][g][t]); }
      gmax[(size_t)blk * COUT + t] = mx;
      gmin[(size_t)blk * COUT + t] = mn;
    }
  }
}

// ---------------------------------------------------------------------------
// stats finalize (unchanged)
// ---------------------------------------------------------------------------
template <int NBLK>
__global__ __launch_bounds__(256)
void stats_final_kernel(const float* __restrict__ psum, const float* __restrict__ psq,
                        const float* __restrict__ g, const float* __restrict__ be,
                        float* __restrict__ ss_out) {
  const int c = blockIdx.x, t = threadIdx.x;
  float S = 0.f, Q = 0.f;
  for (int i = t; i < NBLK; i += 256) {
    S += psum[(size_t)c * NBLK + i];
    Q += psq [(size_t)c * NBLK + i];
  }
  __shared__ float sS[256], sQ[256];
  sS[t] = S; sQ[t] = Q;
  __syncthreads();
  #pragma unroll
  for (int off = 128; off; off >>= 1) {
    if (t < off) { sS[t] += sS[t + off]; sQ[t] += sQ[t + off]; }
    __syncthreads();
  }
  if (t == 0) {
    const float inv = 1.0f / 262144.0f;
    float mean = sS[0] * inv;
    float var = sQ[0] * inv - mean * mean;
    float scale = g[c] / sqrtf(var + 1e-3f);
    ss_out[c] = scale;
    ss_out[128 + c] = be[c] - mean * scale;
  }
}

// pool finalize (unchanged)
__global__ __launch_bounds__(128)
void pool_final_kernel(const float* __restrict__ gmax, const float* __restrict__ gmin,
                       const float* __restrict__ ss2, float* __restrict__ out1) {
  const int blk = blockIdx.x, c = threadIdx.x;
  const float sc = ss2[c], sh = ss2[128 + c];
  float v = (sc >= 0.f) ? gmax[(size_t)blk * C3 + c] : gmin[(size_t)blk * C3 + c];
  out1[(size_t)blk * C3 + c] = fmaxf(fmaf(v, sc, sh), 0.f);
}

extern "C" void kernel_launch(void* const* d_in, const int* in_sizes, int n_in,
                              void* d_out, int out_size, void* d_ws, size_t ws_size,
                              hipStream_t stream) {
  const float* xyz = (const float*)d_in[0];
  const float* pts = (const float*)d_in[1];
  const float* w0 = (const float*)d_in[2];
  const float* b0 = (const float*)d_in[3];
  const float* g0 = (const float*)d_in[4];
  const float* be0 = (const float*)d_in[5];
  const float* w1 = (const float*)d_in[6];
  const float* b1 = (const float*)d_in[7];
  const float* g1 = (const float*)d_in[8];
  const float* be1 = (const float*)d_in[9];
  const float* w2 = (const float*)d_in[10];
  const float* b2 = (const float*)d_in[11];
  const float* g2 = (const float*)d_in[12];
  const float* be2 = (const float*)d_in[13];

  float* out = (float*)d_out;
  float* cent = out;                       // [8,1024,3]
  float* out1 = out + (size_t)NB * NC * 3; // [8,1024,128]

  char* ws = (char*)d_ws;
  float* ssA  = (float*)(ws + OFF_SS);
  float* h0   = (float*)(ws + OFF_H0);
  float* y0   = (float*)(ws + OFF_Y0);
  float* y1   = (float*)(ws + OFF_Y1);
  float* psum = (float*)(ws + OFF_PSUM);
  float* psq  = (float*)(ws + OFF_PSQ);
  float* gmx  = (float*)(ws + OFF_GMX);
  float* gmn  = (float*)(ws + OFF_GMN);

  fps_kernel<<<dim3(NB), dim3(256), 0, stream>>>(xyz, cent);
  ball_kernel<<<dim3(NB * NC), dim3(256), 0, stream>>>(xyz, pts, cent, h0);

  dense0_kernel<<<dim3(ROWS_TOT / 64), dim3(256), 0, stream>>>(h0, w0, b0, y0, psum, psq);
  stats_final_kernel<4096><<<dim3(64), dim3(256), 0, stream>>>(psum, psq, g0, be0, ssA + 0 * 256);

  dense_mid_kernel<64, 64, 16, 4096, false><<<dim3(ROWS_TOT / 64), dim3(256), 0, stream>>>(
      y0, ssA + 0 * 256, w1, b1, y1, psum, psq, nullptr, nullptr);
  stats_final_kernel<4096><<<dim3(64), dim3(256), 0, stream>>>(psum, psq, g1, be1, ssA + 1 * 256);

  dense_mid_kernel<32, 128, 32, 8192, true><<<dim3(ROWS_TOT / 32), dim3(256), 0, stream>>>(
      y1, ssA + 1 * 256, w2, b2, nullptr, psum, psq, gmx, gmn);
  stats_final_kernel<8192><<<dim3(128), dim3(256), 0, stream>>>(psum, psq, g2, be2, ssA + 2 * 256);

  pool_final_kernel<<<dim3(NB * NC), dim3(128), 0, stream>>>(gmx, gmn, ssA + 2 * 256, out1);

  (void)in_sizes; (void)n_in; (void)out_size; (void)ws_size;
}